// Round 1
// baseline (1475.721 us; speedup 1.0000x reference)
//
#include <hip/hip_runtime.h>

#define N_RAYS 16384

__device__ __forceinline__ float softplusf_(float x) {
    // jax.nn.softplus = logaddexp(x, 0) = max(x,0) + log1p(exp(-|x|))
    return fmaxf(x, 0.f) + log1pf(expf(-fabsf(x)));
}

__device__ __forceinline__ float sigmoidf_(float x) {
    // expit: x>=0: 1/(1+exp(-x)); x<0: exp(x)/(1+exp(x))
    float e = expf(-fabsf(x));
    return (x >= 0.f ? 1.f : e) / (1.f + e);
}

__device__ __forceinline__ float scan_mul64(float x, int lane) {
#pragma unroll
    for (int d = 1; d < 64; d <<= 1) {
        float y = __shfl_up(x, d, 64);
        if (lane >= d) x *= y;
    }
    return x;
}

__device__ __forceinline__ float scan_add64(float x, int lane) {
#pragma unroll
    for (int d = 1; d < 64; d <<= 1) {
        float y = __shfl_up(x, d, 64);
        if (lane >= d) x += y;
    }
    return x;
}

// Full SDF MLP eval for one point (one lane). Returns raw MLP output (pre 0.1* scale).
__device__ __forceinline__ float sdf_mlp(float px, float py, float pz,
                                         const float* __restrict__ w1, const float* __restrict__ b1,
                                         const float* __restrict__ w2, const float* __restrict__ b2,
                                         const float* __restrict__ w3, float b3v) {
    float acc[64];
#pragma unroll
    for (int j = 0; j < 64; j++) acc[j] = b2[j];
#pragma unroll 2
    for (int k = 0; k < 64; k++) {
        float a = b1[k];
        a = fmaf(px, w1[k], a);
        a = fmaf(py, w1[64 + k], a);
        a = fmaf(pz, w1[128 + k], a);
        float h = softplusf_(a);
        const float* row = w2 + (k << 6);
#pragma unroll
        for (int j = 0; j < 64; j++) acc[j] = fmaf(h, row[j], acc[j]);
    }
    float out = b3v;
#pragma unroll
    for (int j = 0; j < 64; j++) out = fmaf(softplusf_(acc[j]), w3[j], out);
    return out;
}

__global__ __launch_bounds__(64) void neus_render_kernel(
    const float* __restrict__ rays_o, const float* __restrict__ rays_d,
    const float* __restrict__ nearp, const float* __restrict__ farp,
    const float* __restrict__ sptr,
    const float* __restrict__ sw1, const float* __restrict__ sb1,
    const float* __restrict__ sw2, const float* __restrict__ sb2,
    const float* __restrict__ sw3, const float* __restrict__ sb3,
    const float* __restrict__ rw1, const float* __restrict__ rb1,
    const float* __restrict__ rw2, const float* __restrict__ rb2,
    float* __restrict__ outp) {
    const int ray = blockIdx.x;
    const int lane = threadIdx.x;

    __shared__ float d_lds[128], sdf_lds[128];
    __shared__ float d2[128], sdf2[128];
    __shared__ float tmp1[128], tmp2[128];
    __shared__ float cdfb[129];
    __shared__ float dfine[16], sdffine[16];
    __shared__ float h1b[16 * 68];  // padded: stride 68 -> 2-way bank alias only (free)

    float ox = rays_o[ray * 3], oy = rays_o[ray * 3 + 1], oz = rays_o[ray * 3 + 2];
    float dxv = rays_d[ray * 3], dyv = rays_d[ray * 3 + 1], dzv = rays_d[ray * 3 + 2];
    float nrm = sqrtf(dxv * dxv + dyv * dyv + dzv * dzv);
    dxv /= nrm; dyv /= nrm; dzv /= nrm;
    const float nearv = nearp[ray], farv = farp[ray];
    const float sb3v = sb3[0];

    // ---- coarse: 64 samples, one per lane ----
    {
        float t = (float)lane / 63.f;
        float dc = nearv * (1.f - t) + farv * t;
        float px = fmaf(dc, dxv, ox), py = fmaf(dc, dyv, oy), pz = fmaf(dc, dzv, oz);
        float o_ = sdf_mlp(px, py, pz, sw1, sb1, sw2, sb2, sw3, sb3v);
        d_lds[lane] = dc;
        sdf_lds[lane] = sqrtf(px * px + py * py + pz * pz) - 0.8f + 0.1f * o_;
    }
    __syncthreads();

    int M = 64;
#pragma unroll 1
    for (int it = 0; it < 4; ++it) {
        const float s_it = 64.f * (float)(1 << it);
        const int nI = M - 1;

        // dot_val
        for (int i = lane; i < nI; i += 64)
            tmp1[i] = (sdf_lds[i + 1] - sdf_lds[i]) / (d_lds[i + 1] - d_lds[i] + 1e-5f);
        __syncthreads();
        // alpha
        for (int i = lane; i < nI; i += 64) {
            float dv = tmp1[i];
            float pdv = (i == 0) ? 0.f : tmp1[i - 1];
            dv = fminf(pdv, dv);
            dv = fminf(fmaxf(dv, -10.f), 0.f);  // clip(-10, 0)
            float mid = (sdf_lds[i] + sdf_lds[i + 1]) * 0.5f;
            float dist = d_lds[i + 1] - d_lds[i];
            float pe = mid - dv * dist * 0.5f;
            float ne = mid + dv * dist * 0.5f;
            float pc = sigmoidf_(pe * s_it);
            float nc = sigmoidf_(ne * s_it);
            tmp2[i] = (pc - nc + 1e-5f) / (pc + 1e-5f);
        }
        __syncthreads();

        // weights = alpha * exclusive_cumprod(1 - alpha + 1e-10); p = w + 1e-5
        float a0 = (lane < nI) ? tmp2[lane] : 0.f;
        float a1 = (64 + lane < nI) ? tmp2[64 + lane] : 0.f;
        float x0 = (lane < nI) ? (1.f - a0 + 1e-10f) : 1.f;
        float x1 = (64 + lane < nI) ? (1.f - a1 + 1e-10f) : 1.f;
        float sc0 = scan_mul64(x0, lane);
        float sc1 = scan_mul64(x1, lane);
        float tot0 = __shfl(sc0, 63, 64);
        float e0 = __shfl_up(sc0, 1, 64); if (lane == 0) e0 = 1.f;
        float e1 = __shfl_up(sc1, 1, 64); if (lane == 0) e1 = 1.f;
        e1 *= tot0;
        float p0 = (lane < nI) ? (a0 * e0 + 1e-5f) : 0.f;
        float p1 = (64 + lane < nI) ? (a1 * e1 + 1e-5f) : 0.f;
        float c0 = scan_add64(p0, lane);
        float c1 = scan_add64(p1, lane);
        float T0 = __shfl(c0, 63, 64);
        float T1 = __shfl(c1, 63, 64);
        float S = T0 + T1;
        if (lane == 0) cdfb[0] = 0.f;
        if (lane < nI) cdfb[1 + lane] = c0 / S;
        if (64 + lane < nI) cdfb[1 + 64 + lane] = (c1 + T0) / S;
        __syncthreads();

        // inverse-CDF sample 16 new depths (searchsorted side='right')
        if (lane < 16) {
            float u = (float)lane / 15.f;
            int lo = 0, hi = M;
            while (lo < hi) { int mid = (lo + hi) >> 1; if (cdfb[mid] <= u) lo = mid + 1; else hi = mid; }
            int below = lo - 1; if (below < 0) below = 0; if (below > M - 1) below = M - 1;
            int above = lo; if (above > M - 1) above = M - 1;
            float cb = cdfb[below], ca = cdfb[above];
            float bb = d_lds[below], ba = d_lds[above];
            float den = ca - cb; if (den < 1e-5f) den = 1.f;
            float tt = (u - cb) / den;
            dfine[lane] = bb + tt * (ba - bb);
        }
        __syncthreads();

        // fine SDF eval: 16 samples, 4 lanes cooperate per sample
        {
            int sIdx = lane >> 2, q = lane & 3;
            float dd = dfine[sIdx];
            float px = fmaf(dd, dxv, ox), py = fmaf(dd, dyv, oy), pz = fmaf(dd, dzv, oz);
            // phase A: each lane computes 16 h1 entries for its sample
#pragma unroll 2
            for (int kk = 0; kk < 16; kk++) {
                int k = q * 16 + kk;
                float a = sb1[k];
                a = fmaf(px, sw1[k], a);
                a = fmaf(py, sw1[64 + k], a);
                a = fmaf(pz, sw1[128 + k], a);
                h1b[sIdx * 68 + k] = softplusf_(a);
            }
            __syncthreads();
            // phase B: each lane computes 16 of the 64 hidden-2 outputs
            float acc[16];
#pragma unroll
            for (int jj = 0; jj < 16; jj++) acc[jj] = sb2[q * 16 + jj];
#pragma unroll 2
            for (int k = 0; k < 64; k++) {
                float h = h1b[sIdx * 68 + k];
                const float* row = sw2 + k * 64 + q * 16;
#pragma unroll
                for (int jj = 0; jj < 16; jj++) acc[jj] = fmaf(h, row[jj], acc[jj]);
            }
            float part = 0.f;
#pragma unroll
            for (int jj = 0; jj < 16; jj++) part = fmaf(softplusf_(acc[jj]), sw3[q * 16 + jj], part);
            part += __shfl_xor(part, 1, 64);
            part += __shfl_xor(part, 2, 64);
            if (q == 0) {
                float o_ = sb3v + part;
                sdffine[sIdx] = sqrtf(px * px + py * py + pz * pz) - 0.8f + 0.1f * o_;
            }
        }
        __syncthreads();

        // stable merge of sorted d_lds[0..M) with sorted dfine[0..16)
        for (int i = lane; i < M; i += 64) {
            float v = d_lds[i];
            int cnt = 0;
#pragma unroll
            for (int j = 0; j < 16; j++) cnt += (dfine[j] < v) ? 1 : 0;
            d2[i + cnt] = v; sdf2[i + cnt] = sdf_lds[i];
        }
        if (lane < 16) {
            float v = dfine[lane];
            int lo = 0, hi = M;
            while (lo < hi) { int mid = (lo + hi) >> 1; if (d_lds[mid] <= v) lo = mid + 1; else hi = mid; }
            d2[lo + lane] = v; sdf2[lo + lane] = sdffine[lane];
        }
        __syncthreads();
        M += 16;
        for (int i = lane; i < M; i += 64) { d_lds[i] = d2[i]; sdf_lds[i] = sdf2[i]; }
        __syncthreads();
    }

    // ---- final render (M = 128). Reuse _sdf (bit-identical to the reference's recompute). ----
    const float sfin = sptr[0];
    for (int i = lane; i < 128; i += 64) tmp1[i] = sigmoidf_(sdf_lds[i] * sfin);
    __syncthreads();
    for (int i = lane; i < 127; i += 64) {
        float a = (tmp1[i] - tmp1[i + 1]) / (tmp1[i] + 1e-10f);
        tmp2[i] = fmaxf(a, 0.f);
    }
    __syncthreads();
    float a0 = (lane < 127) ? tmp2[lane] : 0.f;
    float a1 = (64 + lane < 127) ? tmp2[64 + lane] : 0.f;
    float x0 = (lane < 127) ? (1.f - a0 + 1e-10f) : 1.f;
    float x1 = (64 + lane < 127) ? (1.f - a1 + 1e-10f) : 1.f;
    float sc0 = scan_mul64(x0, lane);
    float sc1 = scan_mul64(x1, lane);
    float tot0 = __shfl(sc0, 63, 64);
    float e0 = __shfl_up(sc0, 1, 64); if (lane == 0) e0 = 1.f;
    float e1 = __shfl_up(sc1, 1, 64); if (lane == 0) e1 = 1.f;
    e1 *= tot0;
    float vw0 = a0 * e0;
    float vw1 = a1 * e1;

    float r0 = 0.f, r1 = 0.f, r2 = 0.f;
#pragma unroll 1
    for (int pass = 0; pass < 2; pass++) {
        int i = lane + 64 * pass;
        float vw = pass ? vw1 : vw0;
        if (i < 127) {
            float dm = 0.5f * (d_lds[i + 1] + d_lds[i]);
            float px = fmaf(dm, dxv, ox), py = fmaf(dm, dyv, oy), pz = fmaf(dm, dzv, oz);
            float g0 = rb2[0], g1 = rb2[1], g2 = rb2[2];
#pragma unroll 2
            for (int j = 0; j < 64; j++) {
                float a = rb1[j];
                a = fmaf(px, rw1[j], a);
                a = fmaf(py, rw1[64 + j], a);
                a = fmaf(pz, rw1[128 + j], a);
                a = fmaf(dxv, rw1[192 + j], a);
                a = fmaf(dyv, rw1[256 + j], a);
                a = fmaf(dzv, rw1[320 + j], a);
                float h = softplusf_(a);
                g0 = fmaf(h, rw2[j * 3], g0);
                g1 = fmaf(h, rw2[j * 3 + 1], g1);
                g2 = fmaf(h, rw2[j * 3 + 2], g2);
            }
            r0 = fmaf(vw, sigmoidf_(g0), r0);
            r1 = fmaf(vw, sigmoidf_(g1), r1);
            r2 = fmaf(vw, sigmoidf_(g2), r2);
        }
    }
#pragma unroll
    for (int dd = 1; dd < 64; dd <<= 1) {
        r0 += __shfl_xor(r0, dd, 64);
        r1 += __shfl_xor(r1, dd, 64);
        r2 += __shfl_xor(r2, dd, 64);
    }
    if (lane == 0) {
        outp[ray * 3] = r0;
        outp[ray * 3 + 1] = r1;
        outp[ray * 3 + 2] = r2;
    }
}

extern "C" void kernel_launch(void* const* d_in, const int* in_sizes, int n_in,
                              void* d_out, int out_size, void* d_ws, size_t ws_size,
                              hipStream_t stream) {
    const float* rays_o = (const float*)d_in[0];
    const float* rays_d = (const float*)d_in[1];
    const float* nearp  = (const float*)d_in[2];
    const float* farp   = (const float*)d_in[3];
    const float* sptr   = (const float*)d_in[4];
    const float* sw1    = (const float*)d_in[5];
    const float* sb1    = (const float*)d_in[6];
    const float* sw2    = (const float*)d_in[7];
    const float* sb2    = (const float*)d_in[8];
    const float* sw3    = (const float*)d_in[9];
    const float* sb3    = (const float*)d_in[10];
    const float* rw1    = (const float*)d_in[11];
    const float* rb1    = (const float*)d_in[12];
    const float* rw2    = (const float*)d_in[13];
    const float* rb2    = (const float*)d_in[14];
    float* outp = (float*)d_out;

    neus_render_kernel<<<dim3(N_RAYS), dim3(64), 0, stream>>>(
        rays_o, rays_d, nearp, farp, sptr,
        sw1, sb1, sw2, sb2, sw3, sb3,
        rw1, rb1, rw2, rb2, outp);
}

// Round 2
// 959.479 us; speedup vs baseline: 1.5380x; 1.5380x over previous
//
#include <hip/hip_runtime.h>

#define N_RAYS 16384

typedef float v2f __attribute__((ext_vector_type(2)));

// softplus = max(x,0) + ln2*log2(1 + exp2(-|x|/ln2)) using HW v_exp_f32/v_log_f32 (1 ulp)
__device__ __forceinline__ float softplusf_(float x) {
    float e = __builtin_amdgcn_exp2f(fabsf(x) * -1.44269504088896340736f);
    float l = __builtin_amdgcn_logf(1.f + e);   // log2(1+e)
    return fmaxf(x, 0.f) + 0.69314718055994530942f * l;
}

// sigmoid via HW exp2 + rcp (1 ulp each)
__device__ __forceinline__ float sigmoidf_(float x) {
    float e = __builtin_amdgcn_exp2f(-fabsf(x) * 1.44269504088896340736f);
    float r = __builtin_amdgcn_rcpf(1.f + e);
    return x >= 0.f ? r : e * r;
}

__device__ __forceinline__ float frcp_(float x) { return __builtin_amdgcn_rcpf(x); }

__device__ __forceinline__ float scan_mul64(float x, int lane) {
#pragma unroll
    for (int d = 1; d < 64; d <<= 1) {
        float y = __shfl_up(x, d, 64);
        if (lane >= d) x *= y;
    }
    return x;
}

__device__ __forceinline__ float scan_add64(float x, int lane) {
#pragma unroll
    for (int d = 1; d < 64; d <<= 1) {
        float y = __shfl_up(x, d, 64);
        if (lane >= d) x += y;
    }
    return x;
}

// Full SDF MLP eval for one point (one lane), packed-fp32 inner layer.
__device__ __forceinline__ float sdf_mlp(float px, float py, float pz,
                                         const float* __restrict__ w1, const float* __restrict__ b1,
                                         const float* __restrict__ w2, const float* __restrict__ b2,
                                         const float* __restrict__ w3, float b3v) {
    v2f acc[32];
    const v2f* b2v = (const v2f*)b2;
#pragma unroll
    for (int j = 0; j < 32; j++) acc[j] = b2v[j];
#pragma unroll 4
    for (int k = 0; k < 64; k++) {
        float a = b1[k];
        a = fmaf(px, w1[k], a);
        a = fmaf(py, w1[64 + k], a);
        a = fmaf(pz, w1[128 + k], a);
        float h = softplusf_(a);
        v2f hh = {h, h};
        const v2f* row = (const v2f*)(w2 + (k << 6));
#pragma unroll
        for (int j = 0; j < 32; j++) acc[j] = __builtin_elementwise_fma(hh, row[j], acc[j]);
    }
    float out = b3v;
#pragma unroll
    for (int j = 0; j < 32; j++) {
        out = fmaf(softplusf_(acc[j].x), w3[2 * j], out);
        out = fmaf(softplusf_(acc[j].y), w3[2 * j + 1], out);
    }
    return out;
}

__global__ __launch_bounds__(64) void neus_render_kernel(
    const float* __restrict__ rays_o, const float* __restrict__ rays_d,
    const float* __restrict__ nearp, const float* __restrict__ farp,
    const float* __restrict__ sptr,
    const float* __restrict__ sw1, const float* __restrict__ sb1,
    const float* __restrict__ sw2, const float* __restrict__ sb2,
    const float* __restrict__ sw3, const float* __restrict__ sb3,
    const float* __restrict__ rw1, const float* __restrict__ rb1,
    const float* __restrict__ rw2, const float* __restrict__ rb2,
    float* __restrict__ outp) {
    const int ray = blockIdx.x;
    const int lane = threadIdx.x;

    __shared__ float d_lds[128], sdf_lds[128];
    __shared__ float d2[128], sdf2[128];
    __shared__ float tmp1[128], tmp2[128];
    __shared__ float cdfb[129];
    __shared__ float dfine[16], sdffine[16];
    __shared__ float h1b[16 * 68];  // padded: stride 68 -> 2-way bank alias only (free)

    float ox = rays_o[ray * 3], oy = rays_o[ray * 3 + 1], oz = rays_o[ray * 3 + 2];
    float dxv = rays_d[ray * 3], dyv = rays_d[ray * 3 + 1], dzv = rays_d[ray * 3 + 2];
    float nrm = sqrtf(dxv * dxv + dyv * dyv + dzv * dzv);
    dxv /= nrm; dyv /= nrm; dzv /= nrm;
    const float nearv = nearp[ray], farv = farp[ray];
    const float sb3v = sb3[0];

    // ---- coarse: 64 samples, one per lane ----
    {
        float t = (float)lane / 63.f;
        float dc = nearv * (1.f - t) + farv * t;
        float px = fmaf(dc, dxv, ox), py = fmaf(dc, dyv, oy), pz = fmaf(dc, dzv, oz);
        float o_ = sdf_mlp(px, py, pz, sw1, sb1, sw2, sb2, sw3, sb3v);
        d_lds[lane] = dc;
        sdf_lds[lane] = sqrtf(px * px + py * py + pz * pz) - 0.8f + 0.1f * o_;
    }
    __syncthreads();

    int M = 64;
#pragma unroll 1
    for (int it = 0; it < 4; ++it) {
        const float s_it = 64.f * (float)(1 << it);
        const int nI = M - 1;

        // dot_val
        for (int i = lane; i < nI; i += 64)
            tmp1[i] = (sdf_lds[i + 1] - sdf_lds[i]) * frcp_(d_lds[i + 1] - d_lds[i] + 1e-5f);
        __syncthreads();
        // alpha
        for (int i = lane; i < nI; i += 64) {
            float dv = tmp1[i];
            float pdv = (i == 0) ? 0.f : tmp1[i - 1];
            dv = fminf(pdv, dv);
            dv = fminf(fmaxf(dv, -10.f), 0.f);  // clip(-10, 0)
            float mid = (sdf_lds[i] + sdf_lds[i + 1]) * 0.5f;
            float dist = d_lds[i + 1] - d_lds[i];
            float pe = mid - dv * dist * 0.5f;
            float ne = mid + dv * dist * 0.5f;
            float pc = sigmoidf_(pe * s_it);
            float nc = sigmoidf_(ne * s_it);
            tmp2[i] = (pc - nc + 1e-5f) * frcp_(pc + 1e-5f);
        }
        __syncthreads();

        // weights = alpha * exclusive_cumprod(1 - alpha + 1e-10); p = w + 1e-5
        float a0 = (lane < nI) ? tmp2[lane] : 0.f;
        float a1 = (64 + lane < nI) ? tmp2[64 + lane] : 0.f;
        float x0 = (lane < nI) ? (1.f - a0 + 1e-10f) : 1.f;
        float x1 = (64 + lane < nI) ? (1.f - a1 + 1e-10f) : 1.f;
        float sc0 = scan_mul64(x0, lane);
        float sc1 = scan_mul64(x1, lane);
        float tot0 = __shfl(sc0, 63, 64);
        float e0 = __shfl_up(sc0, 1, 64); if (lane == 0) e0 = 1.f;
        float e1 = __shfl_up(sc1, 1, 64); if (lane == 0) e1 = 1.f;
        e1 *= tot0;
        float p0 = (lane < nI) ? (a0 * e0 + 1e-5f) : 0.f;
        float p1 = (64 + lane < nI) ? (a1 * e1 + 1e-5f) : 0.f;
        float c0 = scan_add64(p0, lane);
        float c1 = scan_add64(p1, lane);
        float T0 = __shfl(c0, 63, 64);
        float T1 = __shfl(c1, 63, 64);
        float S = T0 + T1;
        float rS = 1.f / S;  // precise: CDF feeds searchsorted bin selection
        if (lane == 0) cdfb[0] = 0.f;
        if (lane < nI) cdfb[1 + lane] = c0 * rS;
        if (64 + lane < nI) cdfb[1 + 64 + lane] = (c1 + T0) * rS;
        __syncthreads();

        // inverse-CDF sample 16 new depths (searchsorted side='right')
        if (lane < 16) {
            float u = (float)lane / 15.f;
            int lo = 0, hi = M;
            while (lo < hi) { int mid = (lo + hi) >> 1; if (cdfb[mid] <= u) lo = mid + 1; else hi = mid; }
            int below = lo - 1; if (below < 0) below = 0; if (below > M - 1) below = M - 1;
            int above = lo; if (above > M - 1) above = M - 1;
            float cb = cdfb[below], ca = cdfb[above];
            float bb = d_lds[below], ba = d_lds[above];
            float den = ca - cb; if (den < 1e-5f) den = 1.f;
            float tt = (u - cb) / den;  // precise: sample positions
            dfine[lane] = bb + tt * (ba - bb);
        }
        __syncthreads();

        // fine SDF eval: 16 samples, 4 lanes cooperate per sample
        {
            int sIdx = lane >> 2, q = lane & 3;
            float dd = dfine[sIdx];
            float px = fmaf(dd, dxv, ox), py = fmaf(dd, dyv, oy), pz = fmaf(dd, dzv, oz);
            v2f vpx = {px, px}, vpy = {py, py}, vpz = {pz, pz};
            // phase A: each lane computes its 16 h1 entries (packed pairs)
            const v2f* b1v = (const v2f*)(sb1 + q * 16);
            const v2f* w1a = (const v2f*)(sw1 + q * 16);
            const v2f* w1b = (const v2f*)(sw1 + 64 + q * 16);
            const v2f* w1c = (const v2f*)(sw1 + 128 + q * 16);
#pragma unroll
            for (int kk = 0; kk < 8; kk++) {
                v2f a = b1v[kk];
                a = __builtin_elementwise_fma(vpx, w1a[kk], a);
                a = __builtin_elementwise_fma(vpy, w1b[kk], a);
                a = __builtin_elementwise_fma(vpz, w1c[kk], a);
                v2f h = {softplusf_(a.x), softplusf_(a.y)};
                *(v2f*)(&h1b[sIdx * 68 + q * 16 + 2 * kk]) = h;
            }
            __syncthreads();
            // phase B: each lane computes 16 of the 64 hidden-2 outputs (packed)
            v2f acc[8];
            const v2f* b2v = (const v2f*)(sb2 + q * 16);
#pragma unroll
            for (int jj = 0; jj < 8; jj++) acc[jj] = b2v[jj];
#pragma unroll 4
            for (int k = 0; k < 64; k++) {
                float h = h1b[sIdx * 68 + k];
                v2f hh = {h, h};
                const v2f* row = (const v2f*)(sw2 + k * 64 + q * 16);
#pragma unroll
                for (int jj = 0; jj < 8; jj++) acc[jj] = __builtin_elementwise_fma(hh, row[jj], acc[jj]);
            }
            float part = 0.f;
#pragma unroll
            for (int jj = 0; jj < 8; jj++) {
                part = fmaf(softplusf_(acc[jj].x), sw3[q * 16 + 2 * jj], part);
                part = fmaf(softplusf_(acc[jj].y), sw3[q * 16 + 2 * jj + 1], part);
            }
            part += __shfl_xor(part, 1, 64);
            part += __shfl_xor(part, 2, 64);
            if (q == 0) {
                float o_ = sb3v + part;
                sdffine[sIdx] = sqrtf(px * px + py * py + pz * pz) - 0.8f + 0.1f * o_;
            }
        }
        __syncthreads();

        // stable merge of sorted d_lds[0..M) with sorted dfine[0..16)
        for (int i = lane; i < M; i += 64) {
            float v = d_lds[i];
            int cnt = 0;
#pragma unroll
            for (int j = 0; j < 16; j++) cnt += (dfine[j] < v) ? 1 : 0;
            d2[i + cnt] = v; sdf2[i + cnt] = sdf_lds[i];
        }
        if (lane < 16) {
            float v = dfine[lane];
            int lo = 0, hi = M;
            while (lo < hi) { int mid = (lo + hi) >> 1; if (d_lds[mid] <= v) lo = mid + 1; else hi = mid; }
            d2[lo + lane] = v; sdf2[lo + lane] = sdffine[lane];
        }
        __syncthreads();
        M += 16;
        for (int i = lane; i < M; i += 64) { d_lds[i] = d2[i]; sdf_lds[i] = sdf2[i]; }
        __syncthreads();
    }

    // ---- final render (M = 128). Reuse _sdf (bit-identical to the reference's recompute). ----
    const float sfin = sptr[0];
    for (int i = lane; i < 128; i += 64) tmp1[i] = sigmoidf_(sdf_lds[i] * sfin);
    __syncthreads();
    for (int i = lane; i < 127; i += 64) {
        float a = (tmp1[i] - tmp1[i + 1]) * frcp_(tmp1[i] + 1e-10f);
        tmp2[i] = fmaxf(a, 0.f);
    }
    __syncthreads();
    float a0 = (lane < 127) ? tmp2[lane] : 0.f;
    float a1 = (64 + lane < 127) ? tmp2[64 + lane] : 0.f;
    float x0 = (lane < 127) ? (1.f - a0 + 1e-10f) : 1.f;
    float x1 = (64 + lane < 127) ? (1.f - a1 + 1e-10f) : 1.f;
    float sc0 = scan_mul64(x0, lane);
    float sc1 = scan_mul64(x1, lane);
    float tot0 = __shfl(sc0, 63, 64);
    float e0 = __shfl_up(sc0, 1, 64); if (lane == 0) e0 = 1.f;
    float e1 = __shfl_up(sc1, 1, 64); if (lane == 0) e1 = 1.f;
    e1 *= tot0;
    float vw0 = a0 * e0;
    float vw1 = a1 * e1;

    float r0 = 0.f, r1 = 0.f, r2 = 0.f;
#pragma unroll 1
    for (int pass = 0; pass < 2; pass++) {
        int i = lane + 64 * pass;
        float vw = pass ? vw1 : vw0;
        if (i < 127) {
            float dm = 0.5f * (d_lds[i + 1] + d_lds[i]);
            float px = fmaf(dm, dxv, ox), py = fmaf(dm, dyv, oy), pz = fmaf(dm, dzv, oz);
            v2f vpx = {px, px}, vpy = {py, py}, vpz = {pz, pz};
            v2f vdx = {dxv, dxv}, vdy = {dyv, dyv}, vdz = {dzv, dzv};
            float g0 = rb2[0], g1 = rb2[1], g2 = rb2[2];
            const v2f* b1v = (const v2f*)rb1;
            const v2f* wv0 = (const v2f*)rw1;
            const v2f* wv1 = (const v2f*)(rw1 + 64);
            const v2f* wv2 = (const v2f*)(rw1 + 128);
            const v2f* wv3 = (const v2f*)(rw1 + 192);
            const v2f* wv4 = (const v2f*)(rw1 + 256);
            const v2f* wv5 = (const v2f*)(rw1 + 320);
#pragma unroll 4
            for (int jp = 0; jp < 32; jp++) {
                v2f a = b1v[jp];
                a = __builtin_elementwise_fma(vpx, wv0[jp], a);
                a = __builtin_elementwise_fma(vpy, wv1[jp], a);
                a = __builtin_elementwise_fma(vpz, wv2[jp], a);
                a = __builtin_elementwise_fma(vdx, wv3[jp], a);
                a = __builtin_elementwise_fma(vdy, wv4[jp], a);
                a = __builtin_elementwise_fma(vdz, wv5[jp], a);
                float h0 = softplusf_(a.x);
                float h1 = softplusf_(a.y);
                int j = 2 * jp;
                g0 = fmaf(h0, rw2[j * 3], g0);
                g1 = fmaf(h0, rw2[j * 3 + 1], g1);
                g2 = fmaf(h0, rw2[j * 3 + 2], g2);
                g0 = fmaf(h1, rw2[j * 3 + 3], g0);
                g1 = fmaf(h1, rw2[j * 3 + 4], g1);
                g2 = fmaf(h1, rw2[j * 3 + 5], g2);
            }
            r0 = fmaf(vw, sigmoidf_(g0), r0);
            r1 = fmaf(vw, sigmoidf_(g1), r1);
            r2 = fmaf(vw, sigmoidf_(g2), r2);
        }
    }
#pragma unroll
    for (int dd = 1; dd < 64; dd <<= 1) {
        r0 += __shfl_xor(r0, dd, 64);
        r1 += __shfl_xor(r1, dd, 64);
        r2 += __shfl_xor(r2, dd, 64);
    }
    if (lane == 0) {
        outp[ray * 3] = r0;
        outp[ray * 3 + 1] = r1;
        outp[ray * 3 + 2] = r2;
    }
}

extern "C" void kernel_launch(void* const* d_in, const int* in_sizes, int n_in,
                              void* d_out, int out_size, void* d_ws, size_t ws_size,
                              hipStream_t stream) {
    const float* rays_o = (const float*)d_in[0];
    const float* rays_d = (const float*)d_in[1];
    const float* nearp  = (const float*)d_in[2];
    const float* farp   = (const float*)d_in[3];
    const float* sptr   = (const float*)d_in[4];
    const float* sw1    = (const float*)d_in[5];
    const float* sb1    = (const float*)d_in[6];
    const float* sw2    = (const float*)d_in[7];
    const float* sb2    = (const float*)d_in[8];
    const float* sw3    = (const float*)d_in[9];
    const float* sb3    = (const float*)d_in[10];
    const float* rw1    = (const float*)d_in[11];
    const float* rb1    = (const float*)d_in[12];
    const float* rw2    = (const float*)d_in[13];
    const float* rb2    = (const float*)d_in[14];
    float* outp = (float*)d_out;

    neus_render_kernel<<<dim3(N_RAYS), dim3(64), 0, stream>>>(
        rays_o, rays_d, nearp, farp, sptr,
        sw1, sb1, sw2, sb2, sw3, sb3,
        rw1, rb1, rw2, rb2, outp);
}

// Round 3
// 490.762 us; speedup vs baseline: 3.0070x; 1.9551x over previous
//
#include <hip/hip_runtime.h>

#define N_RAYS 16384

typedef float v2f __attribute__((ext_vector_type(2)));
typedef float v4f __attribute__((ext_vector_type(4)));

// LDS weight layout (float offsets)
#define W1I   0        // [64][4] : {w1x, w1y, w1z, b1}
#define W2    256      // [64][64] row-major
#define B2    4352     // [64]
#define W3    4416     // [64]
#define RW1   4480     // [64][8] : {w0..w5, rb1, pad}
#define RW2   4992     // [64][4] : {rw2[j][0..2], pad}
#define WTOT  5248

__device__ __forceinline__ float softplusf_(float x) {
    float e = __builtin_amdgcn_exp2f(fabsf(x) * -1.44269504088896340736f);
    float l = __builtin_amdgcn_logf(1.f + e);   // log2(1+e)
    return fmaxf(x, 0.f) + 0.69314718055994530942f * l;
}

__device__ __forceinline__ float sigmoidf_(float x) {
    float e = __builtin_amdgcn_exp2f(-fabsf(x) * 1.44269504088896340736f);
    float r = __builtin_amdgcn_rcpf(1.f + e);
    return x >= 0.f ? r : e * r;
}

__device__ __forceinline__ float frcp_(float x) { return __builtin_amdgcn_rcpf(x); }

__device__ __forceinline__ float scan_mul64(float x, int lane) {
#pragma unroll
    for (int d = 1; d < 64; d <<= 1) {
        float y = __shfl_up(x, d, 64);
        if (lane >= d) x *= y;
    }
    return x;
}

__device__ __forceinline__ float scan_add64(float x, int lane) {
#pragma unroll
    for (int d = 1; d < 64; d <<= 1) {
        float y = __shfl_up(x, d, 64);
        if (lane >= d) x += y;
    }
    return x;
}

__global__ __launch_bounds__(256, 4) void neus_render_kernel(
    const float* __restrict__ rays_o, const float* __restrict__ rays_d,
    const float* __restrict__ nearp, const float* __restrict__ farp,
    const float* __restrict__ sptr,
    const float* __restrict__ sw1, const float* __restrict__ sb1,
    const float* __restrict__ sw2, const float* __restrict__ sb2,
    const float* __restrict__ sw3, const float* __restrict__ sb3,
    const float* __restrict__ rw1, const float* __restrict__ rb1,
    const float* __restrict__ rw2, const float* __restrict__ rb2,
    float* __restrict__ outp) {
    const int tid = threadIdx.x;
    const int wave = tid >> 6;
    const int lane = tid & 63;
    const int ray = blockIdx.x * 4 + wave;

    __shared__ float wl[WTOT];
    __shared__ float d_lds[4][128], sdf_lds[4][128];
    __shared__ float d2[4][128], sdf2[4][128];
    __shared__ float tmp1[4][128], tmp2[4][128];
    __shared__ float cdfb[4][132];
    __shared__ float dfine[4][16], sdffine[4][16];

    // ---- cooperative weight staging ----
    for (int i = tid; i < 64; i += 256) {
        wl[W1I + 4 * i + 0] = sw1[i];
        wl[W1I + 4 * i + 1] = sw1[64 + i];
        wl[W1I + 4 * i + 2] = sw1[128 + i];
        wl[W1I + 4 * i + 3] = sb1[i];
        wl[B2 + i] = sb2[i];
        wl[W3 + i] = sw3[i];
        wl[RW1 + 8 * i + 0] = rw1[i];
        wl[RW1 + 8 * i + 1] = rw1[64 + i];
        wl[RW1 + 8 * i + 2] = rw1[128 + i];
        wl[RW1 + 8 * i + 3] = rw1[192 + i];
        wl[RW1 + 8 * i + 4] = rw1[256 + i];
        wl[RW1 + 8 * i + 5] = rw1[320 + i];
        wl[RW1 + 8 * i + 6] = rb1[i];
        wl[RW1 + 8 * i + 7] = 0.f;
        wl[RW2 + 4 * i + 0] = rw2[3 * i];
        wl[RW2 + 4 * i + 1] = rw2[3 * i + 1];
        wl[RW2 + 4 * i + 2] = rw2[3 * i + 2];
        wl[RW2 + 4 * i + 3] = 0.f;
    }
    for (int i = tid; i < 4096; i += 256) wl[W2 + i] = sw2[i];
    __syncthreads();

    float ox = rays_o[ray * 3], oy = rays_o[ray * 3 + 1], oz = rays_o[ray * 3 + 2];
    float dxv = rays_d[ray * 3], dyv = rays_d[ray * 3 + 1], dzv = rays_d[ray * 3 + 2];
    float nrm = sqrtf(dxv * dxv + dyv * dyv + dzv * dzv);
    dxv /= nrm; dyv /= nrm; dzv /= nrm;
    const float nearv = nearp[ray], farv = farp[ray];
    const float sb3v = sb3[0];

    // ---- coarse: 64 samples, one per lane, weights from LDS ----
    {
        float t = (float)lane / 63.f;
        float dc = nearv * (1.f - t) + farv * t;
        float px = fmaf(dc, dxv, ox), py = fmaf(dc, dyv, oy), pz = fmaf(dc, dzv, oz);
        v2f acc[32];
        const v2f* b2v = (const v2f*)&wl[B2];
#pragma unroll
        for (int j = 0; j < 32; j++) acc[j] = b2v[j];
#pragma unroll 4
        for (int k = 0; k < 64; k++) {
            v4f wk = *(const v4f*)&wl[W1I + 4 * k];
            float a = wk.w;
            a = fmaf(px, wk.x, a);
            a = fmaf(py, wk.y, a);
            a = fmaf(pz, wk.z, a);
            float h = softplusf_(a);
            v2f hh = {h, h};
            const v4f* row4 = (const v4f*)&wl[W2 + (k << 6)];
#pragma unroll
            for (int j4 = 0; j4 < 16; j4++) {
                v4f r = row4[j4];
                v2f rlo = {r.x, r.y}, rhi = {r.z, r.w};
                acc[2 * j4] = __builtin_elementwise_fma(hh, rlo, acc[2 * j4]);
                acc[2 * j4 + 1] = __builtin_elementwise_fma(hh, rhi, acc[2 * j4 + 1]);
            }
        }
        float out = sb3v;
#pragma unroll
        for (int j = 0; j < 32; j++) {
            out = fmaf(softplusf_(acc[j].x), wl[W3 + 2 * j], out);
            out = fmaf(softplusf_(acc[j].y), wl[W3 + 2 * j + 1], out);
        }
        d_lds[wave][lane] = dc;
        sdf_lds[wave][lane] = sqrtf(px * px + py * py + pz * pz) - 0.8f + 0.1f * out;
    }
    __syncthreads();

    int M = 64;
#pragma unroll 1
    for (int it = 0; it < 4; ++it) {
        const float s_it = 64.f * (float)(1 << it);
        const int nI = M - 1;

        // dot_val
        for (int i = lane; i < nI; i += 64)
            tmp1[wave][i] = (sdf_lds[wave][i + 1] - sdf_lds[wave][i]) * frcp_(d_lds[wave][i + 1] - d_lds[wave][i] + 1e-5f);
        __syncthreads();
        // alpha
        for (int i = lane; i < nI; i += 64) {
            float dv = tmp1[wave][i];
            float pdv = (i == 0) ? 0.f : tmp1[wave][i - 1];
            dv = fminf(pdv, dv);
            dv = fminf(fmaxf(dv, -10.f), 0.f);
            float mid = (sdf_lds[wave][i] + sdf_lds[wave][i + 1]) * 0.5f;
            float dist = d_lds[wave][i + 1] - d_lds[wave][i];
            float pe = mid - dv * dist * 0.5f;
            float ne = mid + dv * dist * 0.5f;
            float pc = sigmoidf_(pe * s_it);
            float nc = sigmoidf_(ne * s_it);
            tmp2[wave][i] = (pc - nc + 1e-5f) * frcp_(pc + 1e-5f);
        }
        __syncthreads();

        // weights = alpha * exclusive_cumprod(1 - alpha + 1e-10); p = w + 1e-5
        float a0 = (lane < nI) ? tmp2[wave][lane] : 0.f;
        float a1 = (64 + lane < nI) ? tmp2[wave][64 + lane] : 0.f;
        float x0 = (lane < nI) ? (1.f - a0 + 1e-10f) : 1.f;
        float x1 = (64 + lane < nI) ? (1.f - a1 + 1e-10f) : 1.f;
        float sc0 = scan_mul64(x0, lane);
        float sc1 = scan_mul64(x1, lane);
        float tot0 = __shfl(sc0, 63, 64);
        float e0 = __shfl_up(sc0, 1, 64); if (lane == 0) e0 = 1.f;
        float e1 = __shfl_up(sc1, 1, 64); if (lane == 0) e1 = 1.f;
        e1 *= tot0;
        float p0 = (lane < nI) ? (a0 * e0 + 1e-5f) : 0.f;
        float p1 = (64 + lane < nI) ? (a1 * e1 + 1e-5f) : 0.f;
        float c0 = scan_add64(p0, lane);
        float c1 = scan_add64(p1, lane);
        float T0 = __shfl(c0, 63, 64);
        float T1 = __shfl(c1, 63, 64);
        float S = T0 + T1;
        float rS = 1.f / S;  // precise: CDF feeds searchsorted
        if (lane == 0) cdfb[wave][0] = 0.f;
        if (lane < nI) cdfb[wave][1 + lane] = c0 * rS;
        if (64 + lane < nI) cdfb[wave][1 + 64 + lane] = (c1 + T0) * rS;
        __syncthreads();

        // inverse-CDF sample 16 new depths (searchsorted side='right')
        if (lane < 16) {
            float u = (float)lane / 15.f;
            int lo = 0, hi = M;
            while (lo < hi) { int mid = (lo + hi) >> 1; if (cdfb[wave][mid] <= u) lo = mid + 1; else hi = mid; }
            int below = lo - 1; if (below < 0) below = 0; if (below > M - 1) below = M - 1;
            int above = lo; if (above > M - 1) above = M - 1;
            float cb = cdfb[wave][below], ca = cdfb[wave][above];
            float bb = d_lds[wave][below], ba = d_lds[wave][above];
            float den = ca - cb; if (den < 1e-5f) den = 1.f;
            float tt = (u - cb) / den;  // precise: sample positions
            dfine[wave][lane] = bb + tt * (ba - bb);
        }
        __syncthreads();

        // fine SDF eval: 16 samples, 4 lanes per sample; h1 exchanged via shfl
        {
            int sIdx = lane >> 2, q = lane & 3;
            float dd = dfine[wave][sIdx];
            float px = fmaf(dd, dxv, ox), py = fmaf(dd, dyv, oy), pz = fmaf(dd, dzv, oz);
            // phase A: this lane computes h1 for k in [q*16, q*16+16)
            float h1r[16];
#pragma unroll
            for (int kk = 0; kk < 16; kk++) {
                v4f wk = *(const v4f*)&wl[W1I + 4 * (q * 16 + kk)];
                float a = wk.w;
                a = fmaf(px, wk.x, a);
                a = fmaf(py, wk.y, a);
                a = fmaf(pz, wk.z, a);
                h1r[kk] = softplusf_(a);
            }
            // phase B: k-sequential accumulation of this lane's 16 outputs
            v2f acc[8];
            const v2f* b2s = (const v2f*)&wl[B2 + q * 16];
#pragma unroll
            for (int jj = 0; jj < 8; jj++) acc[jj] = b2s[jj];
#pragma unroll
            for (int k = 0; k < 64; k++) {
                float h = __shfl(h1r[k & 15], (sIdx << 2) + (k >> 4), 64);
                v2f hh = {h, h};
                const v4f* row = (const v4f*)&wl[W2 + (k << 6) + q * 16];
#pragma unroll
                for (int j4 = 0; j4 < 4; j4++) {
                    v4f r = row[j4];
                    v2f rlo = {r.x, r.y}, rhi = {r.z, r.w};
                    acc[2 * j4] = __builtin_elementwise_fma(hh, rlo, acc[2 * j4]);
                    acc[2 * j4 + 1] = __builtin_elementwise_fma(hh, rhi, acc[2 * j4 + 1]);
                }
            }
            float part = 0.f;
#pragma unroll
            for (int jj = 0; jj < 8; jj++) {
                part = fmaf(softplusf_(acc[jj].x), wl[W3 + q * 16 + 2 * jj], part);
                part = fmaf(softplusf_(acc[jj].y), wl[W3 + q * 16 + 2 * jj + 1], part);
            }
            part += __shfl_xor(part, 1, 64);
            part += __shfl_xor(part, 2, 64);
            if (q == 0) {
                float o_ = sb3v + part;
                sdffine[wave][sIdx] = sqrtf(px * px + py * py + pz * pz) - 0.8f + 0.1f * o_;
            }
        }
        __syncthreads();

        // stable merge of sorted d_lds[0..M) with sorted dfine[0..16)
        for (int i = lane; i < M; i += 64) {
            float v = d_lds[wave][i];
            int cnt = 0;
#pragma unroll
            for (int j = 0; j < 16; j++) cnt += (dfine[wave][j] < v) ? 1 : 0;
            d2[wave][i + cnt] = v; sdf2[wave][i + cnt] = sdf_lds[wave][i];
        }
        if (lane < 16) {
            float v = dfine[wave][lane];
            int lo = 0, hi = M;
            while (lo < hi) { int mid = (lo + hi) >> 1; if (d_lds[wave][mid] <= v) lo = mid + 1; else hi = mid; }
            d2[wave][lo + lane] = v; sdf2[wave][lo + lane] = sdffine[wave][lane];
        }
        __syncthreads();
        M += 16;
        for (int i = lane; i < M; i += 64) { d_lds[wave][i] = d2[wave][i]; sdf_lds[wave][i] = sdf2[wave][i]; }
        __syncthreads();
    }

    // ---- final render (M = 128); reuse _sdf ----
    const float sfin = sptr[0];
    for (int i = lane; i < 128; i += 64) tmp1[wave][i] = sigmoidf_(sdf_lds[wave][i] * sfin);
    __syncthreads();
    for (int i = lane; i < 127; i += 64) {
        float a = (tmp1[wave][i] - tmp1[wave][i + 1]) * frcp_(tmp1[wave][i] + 1e-10f);
        tmp2[wave][i] = fmaxf(a, 0.f);
    }
    __syncthreads();
    float a0 = (lane < 127) ? tmp2[wave][lane] : 0.f;
    float a1 = (64 + lane < 127) ? tmp2[wave][64 + lane] : 0.f;
    float x0 = (lane < 127) ? (1.f - a0 + 1e-10f) : 1.f;
    float x1 = (64 + lane < 127) ? (1.f - a1 + 1e-10f) : 1.f;
    float sc0 = scan_mul64(x0, lane);
    float sc1 = scan_mul64(x1, lane);
    float tot0 = __shfl(sc0, 63, 64);
    float e0 = __shfl_up(sc0, 1, 64); if (lane == 0) e0 = 1.f;
    float e1 = __shfl_up(sc1, 1, 64); if (lane == 0) e1 = 1.f;
    e1 *= tot0;
    float vw0 = a0 * e0;
    float vw1 = a1 * e1;

    const float rb2x = rb2[0], rb2y = rb2[1], rb2z = rb2[2];
    float r0 = 0.f, r1 = 0.f, r2 = 0.f;
#pragma unroll 1
    for (int pass = 0; pass < 2; pass++) {
        int i = lane + 64 * pass;
        float vw = pass ? vw1 : vw0;
        if (i < 127) {
            float dm = 0.5f * (d_lds[wave][i + 1] + d_lds[wave][i]);
            float px = fmaf(dm, dxv, ox), py = fmaf(dm, dyv, oy), pz = fmaf(dm, dzv, oz);
            float g0 = rb2x, g1 = rb2y, g2 = rb2z;
#pragma unroll 4
            for (int j = 0; j < 64; j++) {
                v4f wa = *(const v4f*)&wl[RW1 + 8 * j];
                v4f wb = *(const v4f*)&wl[RW1 + 8 * j + 4];
                float a = wb.z;
                a = fmaf(px, wa.x, a);
                a = fmaf(py, wa.y, a);
                a = fmaf(pz, wa.z, a);
                a = fmaf(dxv, wa.w, a);
                a = fmaf(dyv, wb.x, a);
                a = fmaf(dzv, wb.y, a);
                float h = softplusf_(a);
                v4f wc = *(const v4f*)&wl[RW2 + 4 * j];
                g0 = fmaf(h, wc.x, g0);
                g1 = fmaf(h, wc.y, g1);
                g2 = fmaf(h, wc.z, g2);
            }
            r0 = fmaf(vw, sigmoidf_(g0), r0);
            r1 = fmaf(vw, sigmoidf_(g1), r1);
            r2 = fmaf(vw, sigmoidf_(g2), r2);
        }
    }
#pragma unroll
    for (int dd = 1; dd < 64; dd <<= 1) {
        r0 += __shfl_xor(r0, dd, 64);
        r1 += __shfl_xor(r1, dd, 64);
        r2 += __shfl_xor(r2, dd, 64);
    }
    if (lane == 0) {
        outp[ray * 3] = r0;
        outp[ray * 3 + 1] = r1;
        outp[ray * 3 + 2] = r2;
    }
}

extern "C" void kernel_launch(void* const* d_in, const int* in_sizes, int n_in,
                              void* d_out, int out_size, void* d_ws, size_t ws_size,
                              hipStream_t stream) {
    const float* rays_o = (const float*)d_in[0];
    const float* rays_d = (const float*)d_in[1];
    const float* nearp  = (const float*)d_in[2];
    const float* farp   = (const float*)d_in[3];
    const float* sptr   = (const float*)d_in[4];
    const float* sw1    = (const float*)d_in[5];
    const float* sb1    = (const float*)d_in[6];
    const float* sw2    = (const float*)d_in[7];
    const float* sb2    = (const float*)d_in[8];
    const float* sw3    = (const float*)d_in[9];
    const float* sb3    = (const float*)d_in[10];
    const float* rw1    = (const float*)d_in[11];
    const float* rb1    = (const float*)d_in[12];
    const float* rw2    = (const float*)d_in[13];
    const float* rb2    = (const float*)d_in[14];
    float* outp = (float*)d_out;

    neus_render_kernel<<<dim3(N_RAYS / 4), dim3(256), 0, stream>>>(
        rays_o, rays_d, nearp, farp, sptr,
        sw1, sb1, sw2, sb2, sw3, sb3,
        rw1, rb1, rw2, rb2, outp);
}